// Round 2
// baseline (293.702 us; speedup 1.0000x reference)
//
#include <hip/hip_runtime.h>

typedef __bf16 bf16_t;
typedef __bf16 bf16x8 __attribute__((ext_vector_type(8)));
typedef __bf16 bf16x4 __attribute__((ext_vector_type(4)));
typedef float f32x4 __attribute__((ext_vector_type(4)));

#define MFMA16(a, b, c) __builtin_amdgcn_mfma_f32_16x16x32_bf16((a), (b), (c), 0, 0, 0)

namespace {
constexpr int S_LEN = 2048;
constexpr int EMB   = 1024;
constexpr int HEADS = 16;
constexpr int HD    = 64;
constexpr float QK_SCALE   = 1.0f / 32.0f;      // 1/sqrt(EMBED)
constexpr float NEG_SCALED = -3.125e18f;        // -1e20 / 32
constexpr float L2E        = 1.44269504088896340736f;
}

// load 8 contiguous fp32 and round to bf16x8
__device__ __forceinline__ bf16x8 load8_cvt(const float* __restrict__ p) {
    const f32x4 a = *(const f32x4*)p;
    const f32x4 b = *(const f32x4*)(p + 4);
    bf16x8 r;
    r[0] = (bf16_t)a[0]; r[1] = (bf16_t)a[1]; r[2] = (bf16_t)a[2]; r[3] = (bf16_t)a[3];
    r[4] = (bf16_t)b[0]; r[5] = (bf16_t)b[1]; r[6] = (bf16_t)b[2]; r[7] = (bf16_t)b[3];
    return r;
}

// --------------------------------------------------------------------------
// Kernel 1: per-head projections (fp32 in -> bf16 out).
//   mat 0: Qp[nh][s][d]  = queries @ Wq^T   (A = token rows, B = Wq rows)
//   mat 1: Kp[nh][s][d]  = keys    @ Wk^T
//   mat 2: VpT[nh][d][s] = (values @ Wv^T)^T  (A = Wv rows, B = token cols)
// grid = 3 * 16 * 64 blocks, 256 threads. Each wave: 16 tokens x 64 outs.
// --------------------------------------------------------------------------
__global__ __launch_bounds__(256) void proj_kernel(
    const float* __restrict__ values, const float* __restrict__ keys,
    const float* __restrict__ queries,
    const float* __restrict__ Wv, const float* __restrict__ Wk,
    const float* __restrict__ Wq,
    bf16_t* __restrict__ Qp, bf16_t* __restrict__ Kp, bf16_t* __restrict__ VpT)
{
    const int tid = threadIdx.x;
    const int w = tid >> 6, l = tid & 63, g = l >> 4, q15 = l & 15;
    const int b   = blockIdx.x;
    const int mat = b >> 10;          // 0=Q, 1=K, 2=V
    const int rem = b & 1023;
    const int h   = rem >> 6;
    const int t0  = (((rem & 63) << 2) + w) << 4;  // token base (16-aligned)
    const int n   = t0 >> 11;
    const int s0  = t0 & 2047;

    if (mat < 2) {
        const float* X = (mat == 0) ? queries : keys;
        const float* W = (mat == 0) ? Wq : Wk;
        bf16_t* O = ((mat == 0) ? Qp : Kp) + (size_t)(n * HEADS + h) * S_LEN * HD;
        // A frags: 16 token rows, contraction d
        const float* xr = X + (size_t)(t0 + q15) * EMB + h * HD + g * 8;
        bf16x8 a0 = load8_cvt(xr);
        bf16x8 a1 = load8_cvt(xr + 32);
        f32x4 acc[4];
        #pragma unroll
        for (int nt = 0; nt < 4; ++nt) acc[nt] = (f32x4){0.f, 0.f, 0.f, 0.f};
        #pragma unroll
        for (int nt = 0; nt < 4; ++nt) {
            const float* wr = W + (nt * 16 + q15) * HD + g * 8;
            bf16x8 b0 = load8_cvt(wr);
            bf16x8 b1 = load8_cvt(wr + 32);
            acc[nt] = MFMA16(a0, b0, acc[nt]);
            acc[nt] = MFMA16(a1, b1, acc[nt]);
        }
        // C/D: col = e_local = q15, row = token_local = g*4+r
        #pragma unroll
        for (int nt = 0; nt < 4; ++nt)
            #pragma unroll
            for (int r = 0; r < 4; ++r)
                O[(size_t)(s0 + g * 4 + r) * HD + nt * 16 + q15] = (bf16_t)acc[nt][r];
    } else {
        const float* xr = values + (size_t)(t0 + q15) * EMB + h * HD + g * 8;
        bf16x8 b0 = load8_cvt(xr);
        bf16x8 b1 = load8_cvt(xr + 32);
        bf16_t* O = VpT + (size_t)(n * HEADS + h) * HD * S_LEN;
        f32x4 acc[4];
        #pragma unroll
        for (int et = 0; et < 4; ++et) acc[et] = (f32x4){0.f, 0.f, 0.f, 0.f};
        #pragma unroll
        for (int et = 0; et < 4; ++et) {
            const float* wr = Wv + (et * 16 + q15) * HD + g * 8;
            bf16x8 a0 = load8_cvt(wr);
            bf16x8 a1 = load8_cvt(wr + 32);
            acc[et] = MFMA16(a0, b0, acc[et]);
            acc[et] = MFMA16(a1, b1, acc[et]);
        }
        // C/D: col = token_local = q15, row = e_local = et*16 + g*4 + r
        #pragma unroll
        for (int et = 0; et < 4; ++et)
            #pragma unroll
            for (int r = 0; r < 4; ++r)
                O[(size_t)(et * 16 + g * 4 + r) * S_LEN + s0 + q15] = (bf16_t)acc[et][r];
    }
}

// --------------------------------------------------------------------------
// Kernel 2: flash attention (all operands bf16 from workspace).
// grid = 1024 (bid = qt*32 + nh), 256 threads. Each wave owns 16 q rows;
// KV tiles of 64. Swapped QK^T (S^T = K·Q^T) so q = lane&15 and the softmax
// reduce is shfl_xor(16)+shfl_xor(32). P passes through a per-wave LDS
// buffer (no cross-wave sync needed; DS ops are in-order per wave).
// --------------------------------------------------------------------------
__global__ __launch_bounds__(256) void attn_kernel(
    const bf16_t* __restrict__ Qp, const bf16_t* __restrict__ Kp,
    const bf16_t* __restrict__ VpT, const int* __restrict__ mask,
    bf16_t* __restrict__ AO)
{
    __shared__ bf16_t plds[4][16][72];   // per-wave P rows, stride 72
    const int tid = threadIdx.x;
    const int w = tid >> 6, l = tid & 63, g = l >> 4, q15 = l & 15;
    const int bid = blockIdx.x;
    const int nh = bid & 31, qt = bid >> 5;
    const int n = nh >> 4, h = nh & 15;
    const size_t hb = (size_t)nh * S_LEN * HD;
    const int qb = qt * 64 + w * 16;

    // Q as B-fragments (col = q = lane&15, k = d), held for the whole kernel
    const bf16_t* qr = Qp + hb + (size_t)(qb + q15) * HD + g * 8;
    const bf16x8 qf0 = *(const bf16x8*)(qr);
    const bf16x8 qf1 = *(const bf16x8*)(qr + 32);

    const int* __restrict__ mrow = mask + n * S_LEN;
    const bf16_t* __restrict__ kbase = Kp + hb;
    const bf16_t* __restrict__ vbase = VpT + hb;

    f32x4 acc[4];
    #pragma unroll
    for (int i = 0; i < 4; ++i) acc[i] = (f32x4){0.f, 0.f, 0.f, 0.f};
    float m_run = -INFINITY, l_run = 0.0f;
    bf16_t* prow = &plds[w][q15][0];

    for (int kt = 0; kt < 32; ++kt) {
        const int kb = kt * 64;
        const unsigned long long mb = __ballot(mrow[kb + l] != 0);

        // S^T[k][q] = K · Q^T  (A = K rows, B = Q)
        f32x4 s[4];
        #pragma unroll
        for (int i = 0; i < 4; ++i) s[i] = (f32x4){0.f, 0.f, 0.f, 0.f};
        #pragma unroll
        for (int sub = 0; sub < 4; ++sub) {
            const bf16_t* kp = kbase + (size_t)(kb + sub * 16 + q15) * HD + g * 8;
            s[sub] = MFMA16(*(const bf16x8*)(kp), qf0, s[sub]);
            s[sub] = MFMA16(*(const bf16x8*)(kp + 32), qf1, s[sub]);
        }

        // prefetch V B-fragments early (independent of softmax)
        bf16x8 vf[2][4];
        #pragma unroll
        for (int c = 0; c < 2; ++c)
            #pragma unroll
            for (int ds = 0; ds < 4; ++ds)
                vf[c][ds] = *(const bf16x8*)(vbase + (size_t)(ds * 16 + q15) * S_LEN
                                             + kb + 32 * c + g * 8);

        // online softmax (per-q stats live in lanes sharing q15)
        float sv[4][4];
        float tmax = -INFINITY;
        #pragma unroll
        for (int sub = 0; sub < 4; ++sub)
            #pragma unroll
            for (int r = 0; r < 4; ++r) {
                float v = s[sub][r] * QK_SCALE;
                const int j = sub * 16 + g * 4 + r;
                if (!((mb >> j) & 1ull)) v = NEG_SCALED;
                sv[sub][r] = v;
                tmax = fmaxf(tmax, v);
            }
        tmax = fmaxf(tmax, __shfl_xor(tmax, 16));
        tmax = fmaxf(tmax, __shfl_xor(tmax, 32));
        const float mnew = fmaxf(m_run, tmax);
        const float corr = exp2f((m_run - mnew) * L2E);
        float tsum = 0.0f;
        #pragma unroll
        for (int sub = 0; sub < 4; ++sub) {
            bf16x4 pk;
            #pragma unroll
            for (int r = 0; r < 4; ++r) {
                const float p = exp2f((sv[sub][r] - mnew) * L2E);
                tsum += p;
                pk[r] = (bf16_t)p;
            }
            *(bf16x4*)&prow[sub * 16 + g * 4] = pk;   // P[q][k] row write (8B)
        }
        tsum += __shfl_xor(tsum, 16);
        tsum += __shfl_xor(tsum, 32);
        l_run = l_run * corr + tsum;
        m_run = mnew;

        // rescale O accumulator (rows q = g*4+r)
        float cr[4];
        #pragma unroll
        for (int r = 0; r < 4; ++r) cr[r] = __shfl(corr, g * 4 + r);
        #pragma unroll
        for (int ds = 0; ds < 4; ++ds)
            #pragma unroll
            for (int r = 0; r < 4; ++r) acc[ds][r] *= cr[r];

        asm volatile("" ::: "memory");  // order P writes before P reads

        // O[q][d] += P[q][k] · V[k][d]  (A = P rows from LDS, B = V from VpT)
        #pragma unroll
        for (int c = 0; c < 2; ++c) {
            const bf16x4 plo = *(const bf16x4*)&prow[32 * c + g * 8];
            const bf16x4 phi = *(const bf16x4*)&prow[32 * c + g * 8 + 4];
            bf16x8 pf;
            #pragma unroll
            for (int i = 0; i < 4; ++i) { pf[i] = plo[i]; pf[i + 4] = phi[i]; }
            #pragma unroll
            for (int ds = 0; ds < 4; ++ds)
                acc[ds] = MFMA16(pf, vf[c][ds], acc[ds]);
        }
        asm volatile("" ::: "memory");  // P reads before next-iter writes
    }

    // normalize and write AO[n][s][h][d] via per-wave LDS transpose
    float li[4];
    #pragma unroll
    for (int r = 0; r < 4; ++r) li[r] = 1.0f / __shfl(l_run, g * 4 + r);
    #pragma unroll
    for (int ds = 0; ds < 4; ++ds)
        #pragma unroll
        for (int r = 0; r < 4; ++r)
            plds[w][g * 4 + r][ds * 16 + q15] = (bf16_t)(acc[ds][r] * li[r]);

    asm volatile("" ::: "memory");

    const int qrow = l >> 2, seg = (l & 3) * 16;
    const bf16x8 o0 = *(const bf16x8*)&plds[w][qrow][seg];
    const bf16x8 o1 = *(const bf16x8*)&plds[w][qrow][seg + 8];
    bf16_t* op = AO + (size_t)(n * S_LEN + qb + qrow) * EMB + h * HD + seg;
    *(bf16x8*)(op) = o0;
    *(bf16x8*)(op + 8) = o1;
}

// --------------------------------------------------------------------------
// Kernel 3: out = AO @ Wo^T + bo.  M=4096, N=1024, K=1024. fp32 out.
// 128x128 tile, BK=64, 4 waves (2x2, 64x64 each), XOR-swizzled LDS chunks.
// grid = 256 (m-tile = bid>>3, n-tile = bid&7).
// --------------------------------------------------------------------------
__global__ __launch_bounds__(256) void outproj_kernel(
    const bf16_t* __restrict__ X, const float* __restrict__ Wo,
    const float* __restrict__ bo, float* __restrict__ out)
{
    __shared__ bf16_t Xs[128 * 64];
    __shared__ bf16_t Ws[128 * 64];
    const int tid = threadIdx.x;
    const int w = tid >> 6, l = tid & 63, g = l >> 4, q15 = l & 15;
    const int m0 = (blockIdx.x >> 3) * 128;
    const int n0 = (blockIdx.x & 7) * 128;
    const int wm = (w >> 1) * 64, wn = (w & 1) * 64;

    f32x4 acc[4][4];
    #pragma unroll
    for (int i = 0; i < 4; ++i)
        #pragma unroll
        for (int j = 0; j < 4; ++j) acc[i][j] = (f32x4){0.f, 0.f, 0.f, 0.f};

    for (int k0 = 0; k0 < EMB; k0 += 64) {
        __syncthreads();
        // stage both tiles; phys chunk = logical chunk ^ (row&7)
        #pragma unroll
        for (int j = 0; j < 4; ++j) {
            const int cid = tid + 256 * j;
            const int r = cid >> 3, pc = cid & 7;
            const int sw = (pc ^ (r & 7)) * 8;
            *(bf16x8*)&Xs[r * 64 + sw] =
                *(const bf16x8*)(X + (size_t)(m0 + r) * EMB + k0 + pc * 8);
            *(bf16x8*)&Ws[r * 64 + sw] =
                load8_cvt(Wo + (size_t)(n0 + r) * EMB + k0 + pc * 8);
        }
        __syncthreads();
        #pragma unroll
        for (int c = 0; c < 2; ++c) {
            bf16x8 av[4], bv[4];
            #pragma unroll
            for (int mt = 0; mt < 4; ++mt) {
                const int r = wm + mt * 16 + q15;
                av[mt] = *(const bf16x8*)&Xs[r * 64 + (((4 * c + g) ^ (r & 7)) * 8)];
            }
            #pragma unroll
            for (int nt = 0; nt < 4; ++nt) {
                const int r = wn + nt * 16 + q15;
                bv[nt] = *(const bf16x8*)&Ws[r * 64 + (((4 * c + g) ^ (r & 7)) * 8)];
            }
            #pragma unroll
            for (int mt = 0; mt < 4; ++mt)
                #pragma unroll
                for (int nt = 0; nt < 4; ++nt)
                    acc[mt][nt] = MFMA16(av[mt], bv[nt], acc[mt][nt]);
        }
    }

    float bias[4];
    #pragma unroll
    for (int nt = 0; nt < 4; ++nt) bias[nt] = bo[n0 + wn + nt * 16 + q15];
    #pragma unroll
    for (int mt = 0; mt < 4; ++mt)
        #pragma unroll
        for (int nt = 0; nt < 4; ++nt)
            #pragma unroll
            for (int r = 0; r < 4; ++r)
                out[(size_t)(m0 + wm + mt * 16 + g * 4 + r) * EMB + n0 + wn + nt * 16 + q15]
                    = acc[mt][nt][r] + bias[nt];
}

// --------------------------------------------------------------------------
extern "C" void kernel_launch(void* const* d_in, const int* in_sizes, int n_in,
                              void* d_out, int out_size, void* d_ws, size_t ws_size,
                              hipStream_t stream) {
    const float* values  = (const float*)d_in[0];
    const float* keys    = (const float*)d_in[1];
    const float* queries = (const float*)d_in[2];
    const int*   mask    = (const int*)d_in[3];
    const float* Wv      = (const float*)d_in[4];
    const float* Wk      = (const float*)d_in[5];
    const float* Wq      = (const float*)d_in[6];
    const float* Wo      = (const float*)d_in[7];
    const float* bo      = (const float*)d_in[8];
    float* out = (float*)d_out;

    // workspace: Qp | Kp | VpT | AO, 8 MB each (bf16), 32 MB total
    bf16_t* Qp  = (bf16_t*)d_ws;
    bf16_t* Kp  = Qp  + (size_t)4194304;
    bf16_t* VpT = Kp  + (size_t)4194304;
    bf16_t* AO  = VpT + (size_t)4194304;

    proj_kernel<<<3072, 256, 0, stream>>>(values, keys, queries, Wv, Wk, Wq, Qp, Kp, VpT);
    attn_kernel<<<1024, 256, 0, stream>>>(Qp, Kp, VpT, mask, AO);
    outproj_kernel<<<256, 256, 0, stream>>>(AO, Wo, bo, out);
}